// Round 3
// baseline (2383.813 us; speedup 1.0000x reference)
//
#include <hip/hip_runtime.h>
#include <hip/hip_bf16.h>
#include <math.h>

#define HH 256
#define WW 256
#define HWs 65536
#define DIMc 64
#define RK 32

// wave-internal LDS fence: orders + drains this wave's LDS ops (cross-lane
// visibility within one wave needs no __syncthreads)
#define WSYNC() __asm__ volatile("s_waitcnt lgkmcnt(0)" ::: "memory")

__device__ inline float dot64(const float* __restrict__ w, const float* v) {
    const float4* w4 = (const float4*)w;
    float a = 0.f;
#pragma unroll
    for (int i = 0; i < 16; ++i) {
        float4 ww = w4[i];
        a += ww.x * v[4*i] + ww.y * v[4*i+1] + ww.z * v[4*i+2] + ww.w * v[4*i+3];
    }
    return a;
}
__device__ inline float dot32(const float* __restrict__ w, const float* v) {
    const float4* w4 = (const float4*)w;
    float a = 0.f;
#pragma unroll
    for (int i = 0; i < 8; ++i) {
        float4 ww = w4[i];
        a += ww.x * v[4*i] + ww.y * v[4*i+1] + ww.z * v[4*i+2] + ww.w * v[4*i+3];
    }
    return a;
}

// K1: per-pixel router + all pointwise preprojections (p0->q, p0->kv, p1-gate z).
__global__ __launch_bounds__(256, 3) void k_router(
    const float* __restrict__ x, const float* __restrict__ shr,
    const float* __restrict__ rw, const float* __restrict__ rb,
    const float* __restrict__ p0w, const float* __restrict__ qw,
    const float* __restrict__ kvw, const float* __restrict__ p1w,
    int* __restrict__ eIdx, float* __restrict__ gVal,
    float* __restrict__ qpre, float2* __restrict__ kvpre,
    __hip_bfloat16* __restrict__ zpre)
{
    __shared__ float wl[12544];
    const int tid = threadIdx.x;
    const int p = blockIdx.x * 256 + tid;
    const int b = p >> 16;
    const int hw = p & 0xFFFF;

    for (int i = tid; i < 256;  i += 256) wl[i] = rw[i];
    for (int i = tid; i < 8192; i += 256) wl[256 + i] = p0w[i];
    for (int i = tid; i < 4096; i += 256) wl[8448 + i] = qw[i];
    __syncthreads();

    const float* xb = x + ((size_t)b * DIMc) * HWs + hw;
    float xr[DIMc];
#pragma unroll
    for (int c = 0; c < DIMc; ++c) xr[c] = xb[(size_t)c * HWs];

    float l[4];
#pragma unroll
    for (int e = 0; e < 4; ++e) l[e] = rb[e] + dot64(&wl[e * DIMc], xr);

    float m = fmaxf(fmaxf(l[0], l[1]), fmaxf(l[2], l[3]));
    int e = (l[0] == m) ? 0 : (l[1] == m) ? 1 : (l[2] == m) ? 2 : 3;
    float s = expf(l[0]-m) + expf(l[1]-m) + expf(l[2]-m) + expf(l[3]-m);
    float g = 1.0f / s;
    eIdx[p] = e;
    gVal[p] = g;

    float h1[RK];
    const float* w0 = &wl[256 + e * RK * DIMc];
#pragma unroll
    for (int r = 0; r < RK; ++r) h1[r] = g * dot64(&w0[r * DIMc], xr);

    const float* wq = &wl[8448 + e * RK * RK];
#pragma unroll
    for (int r = 0; r < RK; ++r)
        qpre[((size_t)(b * RK + r)) * HWs + hw] = dot32(&wq[r * RK], h1);

    __syncthreads();
    for (int i = tid; i < 8192; i += 256) wl[i] = kvw[i];
    __syncthreads();

    const float* wk = &wl[e * 2048];
#pragma unroll
    for (int r = 0; r < RK; ++r) {
        float kk = dot32(&wk[r * RK], h1);
        float vv = dot32(&wk[(RK + r) * RK], h1);
        kvpre[((size_t)(b * RK + r)) * HWs + hw] = make_float2(kk, vv);
    }

    __syncthreads();
    for (int i = tid; i < 8192; i += 256) wl[i] = p1w[i];
    __syncthreads();

    const float* sb = shr + ((size_t)b * DIMc) * HWs + hw;
    float sv[DIMc];
#pragma unroll
    for (int c = 0; c < DIMc; ++c) sv[c] = sb[(size_t)c * HWs];
    const float* wp = &wl[e * 2048];
#pragma unroll
    for (int r = 0; r < RK; ++r) {
        float z = g * dot64(&wp[r * DIMc], sv);
        zpre[((size_t)(b * RK + r)) * HWs + hw] = __float2bfloat16(z);
    }
}

// K2: one 256-thread block per 8x8 patch; wave cq owns channels cq*8..cq*8+7
// in a private LDS slice (no intra-loop __syncthreads).
// LDS map (floats): per-wave slice 2320: khm@0(784=196*f4) vh@784(196)
//   qhm@980(400=100*f4) wk4@1380(196) wv4@1576(196) wq4@1772(36) qA@1808(256) kA@2064(256)
// 4 slices = 9280; oOwn@9280(2112 [px][33]); vOwn@11392(2112). Total 13504 f = 54016 B
// -> 3 blocks/CU. Epilogue aliases: fpwL@0(4096) uS@4096(2112) | p2wL@0(8192) | combS@8192(4096).
__global__ __launch_bounds__(256, 3) void k_patch(
    const float* __restrict__ x,
    const int* __restrict__ eIdx, const float* __restrict__ gVal,
    const float* __restrict__ qpre, const float2* __restrict__ kvpre,
    const __hip_bfloat16* __restrict__ zpre,
    const float* __restrict__ qdw, const float* __restrict__ qdb,
    const float* __restrict__ kvdw, const float* __restrict__ kvdb,
    const float* __restrict__ lnw, const float* __restrict__ lnb,
    const float* __restrict__ fpw, const float* __restrict__ fpb,
    const float* __restrict__ p2w,
    const float* __restrict__ outw, const float* __restrict__ outb,
    float* __restrict__ out)
{
    __shared__ float smem[13504];

    const int tid = threadIdx.x;
    const int cq = tid >> 6;
    const int t  = tid & 63;
    const int bid = blockIdx.x;
    const int b  = bid >> 10;
    const int pp = bid & 1023;
    const int py = pp >> 5, px = pp & 31;
    const int y0 = py * 8, x0 = px * 8;
    const int ly = t >> 3, lx = t & 7;
    const int gy = y0 + ly, gx = x0 + lx;
    const int hw = gy * WW + gx;
    const size_t base = (size_t)b * HWs;

    float* oOwnS = smem + 9280;
    float* vOwnS = smem + 11392;

    // ---- expert halo -> per-thread packed codes (eh lives in scratch, dies after) ----
    int* eh = (int*)smem;   // 196 ints, 14x14 halo origin (-3,-3); 4 = invalid
    for (int j = tid; j < 196; j += 256) {
        int r = j / 14, cc = j % 14;
        int yy = y0 - 3 + r, xx = x0 - 3 + cc;
        int v = 4;
        if ((unsigned)yy < HH && (unsigned)xx < WW) v = eIdx[base + yy * WW + xx];
        eh[j] = v;
    }
    __syncthreads();
    const int ep = eh[(ly + 3) * 14 + (lx + 3)];

    // v-mask: bit tap = (code[tap]==ep), taps 0..48
    unsigned m0 = 0u, m1 = 0u;
#pragma unroll
    for (int dy = 0; dy < 7; ++dy)
#pragma unroll
    for (int dx = 0; dx < 7; ++dx) {
        const int tap = dy * 7 + dx;
        unsigned cv = (unsigned)eh[(ly + dy) * 14 + (lx + dx)];
        unsigned bit = (cv == (unsigned)ep) ? 1u : 0u;
        if (tap < 32) m0 |= bit << tap; else m1 |= bit << (tap - 32);
    }
    // staging codes: halo px jj = t + 64*it
    unsigned scK = 0u;
#pragma unroll
    for (int it = 0; it < 4; ++it) {
        int jj = t + it * 64;
        unsigned cv = 4u;
        if (jj < 196) cv = (unsigned)eh[jj];
        scK |= cv << (3 * it);
    }
    unsigned scQ = 0u;
#pragma unroll
    for (int it = 0; it < 2; ++it) {
        int jj = t + it * 64;
        unsigned cv = 4u;
        if (jj < 100) { int r = jj / 10, cc = jj % 10; cv = (unsigned)eh[(r + 2) * 14 + (cc + 2)]; }
        scQ |= cv << (3 * it);
    }
    __syncthreads();   // eh dead; slices may be written

    float* sl  = smem + cq * 2320;
    float* khm = sl;
    float* vh  = sl + 784;
    float* qhm = sl + 980;
    float* wkL = sl + 1380;
    float* wvL = sl + 1576;
    float* wqL = sl + 1772;
    float* qA  = sl + 1808;
    float* kA  = sl + 2064;

#pragma unroll 1
    for (int ch = 0; ch < 8; ++ch) {
        const int c = cq * 8 + ch;
        WSYNC();   // this wave's previous reads of the slice are done

        // ---- stage masked k plane (one-hot f4), raw v plane ----
        const float2* kvp = kvpre + ((size_t)(b * RK + c)) * HWs;
#pragma unroll
        for (int it = 0; it < 4; ++it) {
            int jj = t + it * 64;
            if (jj < 196) {
                int r = jj / 14, cc = jj % 14;
                int yy = y0 - 3 + r, xx = x0 - 3 + cc;
                float kk_ = 0.f, vv_ = 0.f;
                if ((unsigned)yy < HH && (unsigned)xx < WW) {
                    float2 kv = kvp[yy * WW + xx];
                    kk_ = kv.x; vv_ = kv.y;
                }
                unsigned cv = (scK >> (3 * it)) & 7u;
                float4 km;
                km.x = (cv == 0u) ? kk_ : 0.f;
                km.y = (cv == 1u) ? kk_ : 0.f;
                km.z = (cv == 2u) ? kk_ : 0.f;
                km.w = (cv == 3u) ? kk_ : 0.f;
                *(float4*)&khm[jj * 4] = km;
                vh[jj] = vv_;
            }
        }
        // ---- stage masked q plane ----
        const float* qp = qpre + ((size_t)(b * RK + c)) * HWs;
#pragma unroll
        for (int it = 0; it < 2; ++it) {
            int jj = t + it * 64;
            if (jj < 100) {
                int r = jj / 10, cc = jj % 10;
                int yy = y0 - 1 + r, xx = x0 - 1 + cc;
                float qv = 0.f;
                if ((unsigned)yy < HH && (unsigned)xx < WW) qv = qp[yy * WW + xx];
                unsigned cv = (scQ >> (3 * it)) & 7u;
                float4 qm;
                qm.x = (cv == 0u) ? qv : 0.f;
                qm.y = (cv == 1u) ? qv : 0.f;
                qm.z = (cv == 2u) ? qv : 0.f;
                qm.w = (cv == 3u) ? qv : 0.f;
                *(float4*)&qhm[jj * 4] = qm;
            }
        }
        // ---- stage weights [tap][expert] f4 ----
#pragma unroll
        for (int it = 0; it < 4; ++it) {
            int jj = t + it * 64;
            if (jj < 196) {
                int e4 = jj / 49, kk2 = jj % 49;
                wkL[kk2 * 4 + e4] = kvdw[((size_t)(e4 * 64 + c)) * 49 + kk2];
                wvL[kk2 * 4 + e4] = kvdw[((size_t)(e4 * 64 + 32 + c)) * 49 + kk2];
            }
        }
        if (t < 36) { int e4 = t / 9, kk2 = t % 9; wqL[kk2 * 4 + e4] = qdw[(e4 * 32 + c) * 9 + kk2]; }
        WSYNC();   // staging visible within wave

        // ---- dw3: q for all 4 experts (branchless, masked plane) ----
        float qa0 = qdb[c], qa1 = qdb[32 + c], qa2 = qdb[64 + c], qa3 = qdb[96 + c];
#pragma unroll
        for (int i3 = 0; i3 < 3; ++i3)
#pragma unroll
        for (int j3 = 0; j3 < 3; ++j3) {
            float4 qm = *(const float4*)&qhm[((ly + i3) * 10 + (lx + j3)) * 4];
            float4 w4 = *(const float4*)&wqL[(i3 * 3 + j3) * 4];
            qa0 += qm.x * w4.x; qa1 += qm.y * w4.y; qa2 += qm.z * w4.z; qa3 += qm.w * w4.w;
        }

        // ---- dw7: k for all 4 experts + v (own expert via bitmask) ----
        float ka0 = kvdb[c], ka1 = kvdb[64 + c], ka2 = kvdb[128 + c], ka3 = kvdb[192 + c];
        float vb0 = kvdb[32 + c], vb1 = kvdb[96 + c], vb2 = kvdb[160 + c], vb3 = kvdb[224 + c];
        float va = (ep & 2) ? ((ep & 1) ? vb3 : vb2) : ((ep & 1) ? vb1 : vb0);
        const float* wvE = wvL + ep;
#pragma unroll
        for (int dy = 0; dy < 7; ++dy)
#pragma unroll
        for (int dx = 0; dx < 7; ++dx) {
            const int tap = dy * 7 + dx;
            const int hidx = (ly + dy) * 14 + (lx + dx);
            float4 km = *(const float4*)&khm[hidx * 4];
            float4 w4 = *(const float4*)&wkL[tap * 4];
            ka0 += km.x * w4.x; ka1 += km.y * w4.y; ka2 += km.z * w4.z; ka3 += km.w * w4.w;
            unsigned bb = (tap < 32) ? ((m0 >> tap) & 1u) : ((m1 >> (tap - 32)) & 1u);
            va += wvE[tap * 4] * (vh[hidx] * (float)bb);
        }

        qA[t] = qa0; qA[64 + t] = qa1; qA[128 + t] = qa2; qA[192 + t] = qa3;
        kA[t] = ka0; kA[64 + t] = ka1; kA[128 + t] = ka2; kA[192 + t] = ka3;
        vOwnS[t * 33 + c] = va;
        WSYNC();   // qA/kA visible within wave

        // ---- 8x8 circular conv, own expert: oc = sum_sy sum_j q[sy][(lx-j)&7]*k[ky][j] ----
        const float* qAe = qA + ep * 64;
        const float* kAe = kA + ep * 64;
        float oc = 0.f;
#pragma unroll
        for (int sy = 0; sy < 8; ++sy) {
            const int ky = ((ly - sy) & 7) * 8;
            float4 k0 = *(const float4*)&kAe[ky];
            float4 k1 = *(const float4*)&kAe[ky + 4];
            const float* qr = &qAe[sy * 8];
            oc += qr[lx] * k0.x;
            oc += qr[(lx - 1) & 7] * k0.y;
            oc += qr[(lx - 2) & 7] * k0.z;
            oc += qr[(lx - 3) & 7] * k0.w;
            oc += qr[(lx - 4) & 7] * k1.x;
            oc += qr[(lx - 5) & 7] * k1.y;
            oc += qr[(lx - 6) & 7] * k1.z;
            oc += qr[(lx - 7) & 7] * k1.w;
        }
        oOwnS[t * 33 + c] = oc;
    }

    // ---- epilogue ----
    __syncthreads();   // all waves done; oOwn/vOwn coherent; slices dead
    float* fpwL = smem;          // 4096
    float* uS   = smem + 4096;   // 2112, stride 33
    for (int i = tid; i < 4096; i += 256) fpwL[i] = fpw[i];
    __syncthreads();

    float o_[RK], vv_[RK];
#pragma unroll
    for (int c = 0; c < RK; ++c) { o_[c] = oOwnS[t * 33 + c]; vv_[c] = vOwnS[t * 33 + c]; }
    float mu = 0.f;
#pragma unroll
    for (int c = 0; c < RK; ++c) mu += o_[c];
    mu *= (1.0f / RK);
    float var = 0.f;
#pragma unroll
    for (int c = 0; c < RK; ++c) { float d = o_[c] - mu; var += d * d; }
    var *= (1.0f / RK);
    float inv = 1.0f / sqrtf(var + 1e-5f);
    float ttv[RK];
#pragma unroll
    for (int c = 0; c < RK; ++c)
        ttv[c] = ((o_[c] - mu) * inv * lnw[ep * RK + c] + lnb[ep * RK + c]) * vv_[c];

    const float g = gVal[base + hw];

    for (int r8 = 0; r8 < 8; ++r8) {
        const int r = cq * 8 + r8;
        const float4* wr = (const float4*)&fpwL[(ep * 32 + r) * 32];
        float acc = fpb[ep * 32 + r];
#pragma unroll
        for (int i = 0; i < 8; ++i) {
            float4 w4 = wr[i];
            acc += w4.x * ttv[4*i] + w4.y * ttv[4*i+1] + w4.z * ttv[4*i+2] + w4.w * ttv[4*i+3];
        }
        float z = __bfloat162float(zpre[((size_t)(b * RK + r)) * HWs + hw]);
        float gate = z / (1.f + expf(-z));
        uS[t * 33 + r] = acc * gate;
    }
    __syncthreads();
    float u[RK];
#pragma unroll
    for (int r = 0; r < RK; ++r) u[r] = uS[t * 33 + r];
    __syncthreads();

    float* p2wL = smem;          // 8192 (overwrites fpwL+uS; u is in regs)
    for (int i = tid; i < 8192; i += 256) p2wL[i] = p2w[i];
    __syncthreads();

    float comb[16];
    for (int o16 = 0; o16 < 16; ++o16) {
        const int oo = cq * 16 + o16;
        const float4* wr = (const float4*)&p2wL[(ep * 64 + oo) * 32];
        float acc = 0.f;
#pragma unroll
        for (int i = 0; i < 8; ++i) {
            float4 w4 = wr[i];
            acc += w4.x * u[4*i] + w4.y * u[4*i+1] + w4.z * u[4*i+2] + w4.w * u[4*i+3];
        }
        float xv = x[((size_t)(b * DIMc + oo)) * HWs + hw];
        comb[o16] = g * acc + g * g * xv;
    }
    __syncthreads();   // p2wL reads complete everywhere before reuse region written? (combS disjoint; barrier orders writes vs outw reads)

    float* combS = smem + 8192;  // 4096, layout [c][64px]
    for (int o16 = 0; o16 < 16; ++o16)
        combS[(cq * 16 + o16) * 64 + t] = comb[o16];
    __syncthreads();

    float accO[16];
#pragma unroll
    for (int o16 = 0; o16 < 16; ++o16) accO[o16] = outb[cq * 16 + o16];
#pragma unroll 4
    for (int c = 0; c < 64; ++c) {
        float cv = combS[c * 64 + t];
#pragma unroll
        for (int o16 = 0; o16 < 16; ++o16)
            accO[o16] += outw[(cq * 16 + o16) * 64 + c] * cv;   // outw index wave-uniform -> SMEM
    }
    for (int o16 = 0; o16 < 16; ++o16)
        out[((size_t)(b * DIMc + cq * 16 + o16)) * HWs + hw] = accO[o16];
}

extern "C" void kernel_launch(void* const* d_in, const int* in_sizes, int n_in,
                              void* d_out, int out_size, void* d_ws, size_t ws_size,
                              hipStream_t stream) {
    const float* x    = (const float*)d_in[0];
    const float* shr  = (const float*)d_in[1];
    const float* rw   = (const float*)d_in[2];
    const float* rb_  = (const float*)d_in[3];
    const float* p0w  = (const float*)d_in[4];
    const float* p1w  = (const float*)d_in[5];
    const float* p2w  = (const float*)d_in[6];
    const float* qw   = (const float*)d_in[7];
    const float* qdw  = (const float*)d_in[8];
    const float* qdb  = (const float*)d_in[9];
    const float* kvw  = (const float*)d_in[10];
    const float* kvdw = (const float*)d_in[11];
    const float* kvdb = (const float*)d_in[12];
    const float* lnw  = (const float*)d_in[13];
    const float* lnb  = (const float*)d_in[14];
    const float* fpw  = (const float*)d_in[15];
    const float* fpb  = (const float*)d_in[16];
    const float* outw = (const float*)d_in[17];
    const float* outb = (const float*)d_in[18];
    float* out = (float*)d_out;

    const int N = 4 * HWs;
    char* ws = (char*)d_ws;
    int*    eIdx  = (int*)ws;                ws += (size_t)N * sizeof(int);
    float*  gV    = (float*)ws;              ws += (size_t)N * sizeof(float);
    float*  qpre  = (float*)ws;              ws += (size_t)N * RK * sizeof(float);
    float2* kvpre = (float2*)ws;             ws += (size_t)N * RK * sizeof(float2);
    __hip_bfloat16* zpre = (__hip_bfloat16*)ws;

    k_router<<<N / 256, 256, 0, stream>>>(x, shr, rw, rb_, p0w, qw, kvw, p1w,
                                          eIdx, gV, qpre, kvpre, zpre);
    k_patch<<<4 * 32 * 32, 256, 0, stream>>>(x, eIdx, gV, qpre, kvpre, zpre,
                                             qdw, qdb, kvdw, kvdb,
                                             lnw, lnb, fpw, fpb, p2w, outw, outb, out);
}